// Round 2
// baseline (217.724 us; speedup 1.0000x reference)
//
#include <hip/hip_runtime.h>

// J-loss via MFMA: T[b,i,k] = sum_p pred[b,i,p] * onehot(target[b,p]==k)
// j[b] = -sum_{i!=k} log(0.5 + 0.5*(T[b,i,i]/n[b,i] - T[b,i,k]/n[b,k]))
//
// R8 (216.8us): direct strided loads + nt. R9 (216.0us, NULL): grid balance +
// unroll -> kernel is NOT latency/tail-bound.
// R10 theory: direct A-loads are forced by the MFMA fragment layout into
// 16 channel-streams x 589KB stride per instruction (128B consumed per
// stream-visit) -> DRAM row-buffer thrash caps achieved BW (~4 TB/s vs
// fills' 6.9). Fix: LDS-staged tile. Staging reads each channel as a
// contiguous 2KB burst (lane i owns floats [8i,8i+8) -> 2x dwordx4,
// fully coalesced), packs bf16 ONCE at staging, ds_write_b128 into a
// padded tile (row stride 1040B = 260 dw -> every 16-lane phase hits each
// 16B slot exactly 2x = conflict-free for both write and read). K-loop
// then reads A as one ds_read_b128 per fragment. LDS tile 32ch x 512px
// bf16 = 32.5KB single-buffered, aliased with the reduction buffer ->
// still 4 blocks/CU.

#define BB 8
#define CC 32
#define HW 147456                 // 384*384 = 144 * 1024
#define CHUNK_PX 1024             // pixels per block
#define NCHUNK (HW / CHUNK_PX)    // 144 -> grid 1152
#define TILE_PX 512               // staged tile: 512 px x 32 ch bf16
#define NTILE (CHUNK_PX / TILE_PX) // 2
#define ROW_B 1040                // row stride bytes: 512*2 + 16 pad (260 dwords)

typedef __attribute__((ext_vector_type(8))) short short8;
typedef __attribute__((ext_vector_type(4))) float float4v;
typedef __attribute__((ext_vector_type(4))) unsigned uint4v;
typedef __attribute__((ext_vector_type(4))) int int4v;

// pack trunc-bf16(lo), trunc-bf16(hi) into one dword: 1 v_perm_b32
__device__ __forceinline__ unsigned pk(float lo, float hi) {
    return __builtin_amdgcn_perm(__float_as_uint(hi), __float_as_uint(lo), 0x07060302u);
}
// packed pair of one-hot bf16 values for classes (ta,tb) vs m
__device__ __forceinline__ unsigned oh2(int ta, int tb, int m) {
    return (ta == m ? 0x3F80u : 0u) | (tb == m ? 0x3F800000u : 0u);
}

__global__ __launch_bounds__(256, 4) void jloss_mfma(
    const float* __restrict__ pred,    // [B][C][HW]
    const int*   __restrict__ target,  // [B][HW]
    float*       __restrict__ T,       // [B][C][C] pre-zeroed
    float*       __restrict__ cnt)     // [B][C]    pre-zeroed
{
    const int tid  = threadIdx.x;
    const int w    = tid >> 6;         // wave 0..3
    const int l    = tid & 63;
    const int quad = l >> 4;
    const int m    = l & 15;
    const int blk  = blockIdx.x;
    const int b    = blk / NCHUNK;
    const int chunk= blk % NCHUNK;

    const float* predb = pred + (long)b * CC * HW;
    const int*   tgtb  = target + (long)b * HW;

    // LDS tile (32 rows x 1040 B = 33280 B), later aliased as red[4][32][32]
    __shared__ __align__(16) char lds_raw[CC * ROW_B];
    __shared__ float redc[4][CC];

    float4v acc00 = {0,0,0,0}, acc01 = {0,0,0,0};
    float4v acc10 = {0,0,0,0}, acc11 = {0,0,0,0};
    float4v accc0 = {0,0,0,0}, accc1 = {0,0,0,0};   // counts: ones . B
    const short8 ONES = {0x3F80,0x3F80,0x3F80,0x3F80,0x3F80,0x3F80,0x3F80,0x3F80};

    for (int tile = 0; tile < NTILE; ++tile) {
        const long tile_px = (long)chunk * CHUNK_PX + tile * TILE_PX;

        // ---- stage: wave w packs channels 8w..8w+7 into LDS (coalesced) ----
        #pragma unroll
        for (int r = 0; r < 8; ++r) {
            const int ch = w * 8 + r;
            const float* src = predb + (long)ch * HW + tile_px + l * 8;
            const float4v lo = __builtin_nontemporal_load((const float4v*)src);
            const float4v hi = __builtin_nontemporal_load((const float4v*)(src + 4));
            uint4v d;
            d[0] = pk(lo[0], lo[1]); d[1] = pk(lo[2], lo[3]);
            d[2] = pk(hi[0], hi[1]); d[3] = pk(hi[2], hi[3]);
            *(uint4v*)(lds_raw + ch * ROW_B + l * 16) = d;   // ds_write_b128
        }
        __syncthreads();

        // ---- compute: wave w does K-steps 4w..4w+3 of this tile ----
        #pragma unroll
        for (int s = 0; s < 4; ++s) {
            const int ks = w * 4 + s;                        // tile-relative
            const char* arow = lds_raw + ks * 64 + quad * 16;
            const short8 A0 = *(const short8*)(arow + m * ROW_B);
            const short8 A1 = *(const short8*)(arow + (m + 16) * ROW_B);

            const long po = tile_px + ks * 32 + quad * 8;
            const int4v t0 = __builtin_nontemporal_load((const int4v*)(tgtb + po));
            const int4v t1 = __builtin_nontemporal_load((const int4v*)(tgtb + po + 4));

            union { short8 s; uint4v u; } B0, B1;
            B0.u[0] = oh2(t0[0], t0[1], m);      B0.u[1] = oh2(t0[2], t0[3], m);
            B0.u[2] = oh2(t1[0], t1[1], m);      B0.u[3] = oh2(t1[2], t1[3], m);
            const int m16 = m + 16;
            B1.u[0] = oh2(t0[0], t0[1], m16);    B1.u[1] = oh2(t0[2], t0[3], m16);
            B1.u[2] = oh2(t1[0], t1[1], m16);    B1.u[3] = oh2(t1[2], t1[3], m16);

            acc00 = __builtin_amdgcn_mfma_f32_16x16x32_bf16(A0, B0.s, acc00, 0, 0, 0);
            acc01 = __builtin_amdgcn_mfma_f32_16x16x32_bf16(A0, B1.s, acc01, 0, 0, 0);
            acc10 = __builtin_amdgcn_mfma_f32_16x16x32_bf16(A1, B0.s, acc10, 0, 0, 0);
            acc11 = __builtin_amdgcn_mfma_f32_16x16x32_bf16(A1, B1.s, acc11, 0, 0, 0);
            accc0 = __builtin_amdgcn_mfma_f32_16x16x32_bf16(ONES, B0.s, accc0, 0, 0, 0);
            accc1 = __builtin_amdgcn_mfma_f32_16x16x32_bf16(ONES, B1.s, accc1, 0, 0, 0);
        }
        __syncthreads();   // tile consumed; safe to overwrite (and to alias red)
    }

    // cross-wave reduce in LDS (alias onto the tile buffer), then atomics
    float (*red)[CC][CC] = (float (*)[CC][CC])lds_raw;   // 16 KB of 32.5 KB
    #pragma unroll
    for (int r = 0; r < 4; ++r) {      // C layout: row=quad*4+r, col=m (m89-verified)
        red[w][quad*4 + r     ][m     ] = acc00[r];
        red[w][quad*4 + r     ][m + 16] = acc01[r];
        red[w][quad*4 + r + 16][m     ] = acc10[r];
        red[w][quad*4 + r + 16][m + 16] = acc11[r];
    }
    if (quad == 0) {                   // counts: every row of accc is count[col]
        redc[w][m]      = accc0[0];
        redc[w][m + 16] = accc1[0];
    }
    __syncthreads();

    float* Tb = T + (long)b * CC * CC;
    const float* rp = (const float*)lds_raw;
    for (int j = tid; j < CC * CC; j += 256) {
        const float s = rp[j] + rp[1024 + j] + rp[2048 + j] + rp[3072 + j];
        atomicAdd(&Tb[j], s);
    }
    if (tid < CC)
        atomicAdd(&cnt[b * CC + tid],
                  redc[0][tid] + redc[1][tid] + redc[2][tid] + redc[3][tid]);
}

__global__ __launch_bounds__(256) void jloss_final(
    const float* __restrict__ T,
    const float* __restrict__ cnt,
    float*       __restrict__ out)
{
    const int b   = blockIdx.x;
    const int tid = threadIdx.x;
    __shared__ float diag_s[CC];
    __shared__ float inv_n[CC];
    __shared__ float wsum[4];

    const float* Tb = T + (long)b * CC * CC;
    const float* cb = cnt + b * CC;

    if (tid < CC) {
        const float inv = 1.0f / cb[tid];
        inv_n[tid]  = inv;
        diag_s[tid] = Tb[tid * CC + tid] * inv;
    }
    __syncthreads();

    float sum = 0.0f;
    for (int idx = tid; idx < CC * CC; idx += 256) {
        const int i = idx >> 5;
        const int k = idx & 31;
        if (i != k) {
            const float S = Tb[idx] * inv_n[k];
            sum += logf(0.5f + 0.5f * (diag_s[i] - S));
        }
    }
    #pragma unroll
    for (int off = 32; off > 0; off >>= 1) sum += __shfl_down(sum, off, 64);
    if ((tid & 63) == 0) wsum[tid >> 6] = sum;
    __syncthreads();
    if (tid == 0) out[b] = -(wsum[0] + wsum[1] + wsum[2] + wsum[3]);
}

extern "C" void kernel_launch(void* const* d_in, const int* in_sizes, int n_in,
                              void* d_out, int out_size, void* d_ws, size_t ws_size,
                              hipStream_t stream) {
    const float* pred   = (const float*)d_in[0];
    const int*   target = (const int*)d_in[1];
    float* out = (float*)d_out;

    float* T   = (float*)d_ws;                       // 8*32*32 floats
    float* cnt = (float*)d_ws + BB * CC * CC;        // 8*32 floats

    hipMemsetAsync(d_ws, 0, (BB * CC * CC + BB * CC) * sizeof(float), stream);

    jloss_mfma <<<BB * NCHUNK, 256, 0, stream>>>(pred, target, T, cnt);
    jloss_final<<<BB, 256, 0, stream>>>(T, cnt, out);
}